// Round 1
// baseline (165.394 us; speedup 1.0000x reference)
//
#include <hip/hip_runtime.h>

// Problem constants (fixed by the reference setup_inputs):
//   input_tensor: [8, 128, 128, 128, 1] fp32
//   random_u:     [8, 8, 3] fp32
//   SCALE = 0.2
#define NB   8
#define NS   128          // D = H = W = 128
#define VOXELS_PER_B (NS*NS*NS)   // 2^21

// ---------------------------------------------------------------------------
// Kernel 1: per-batch affine transform from noise.
// Key simplification: A has rows [c_n, 1] with c_n the +-1 corners, so
// A^T A = 8*I exactly -> X = (A^T B)/8; transform = X^T.
// transform[b][i][j] = (1/8) * sum_n A[n][j] * Bmat[b][n][i]
//   Bmat[b][n][i<3] = c[n][i] * (0.8 + 0.2*u[b][n][i]);  A[n][j<3]=c[n][j], A[n][3]=1
// We only need rows i=0..2 (12 floats per batch) for the grid warp.
// ---------------------------------------------------------------------------
__global__ void affine_from_noise_kernel(const float* __restrict__ u,
                                         float* __restrict__ T) {
    int b = threadIdx.x;
    if (b >= NB) return;
    float t[3][4];
#pragma unroll
    for (int i = 0; i < 3; ++i)
#pragma unroll
        for (int j = 0; j < 4; ++j) t[i][j] = 0.0f;

#pragma unroll
    for (int n = 0; n < 8; ++n) {
        // format(n,'03b'): bit2 -> coord0, bit1 -> coord1, bit0 -> coord2
        float c0 = (n & 4) ? 1.0f : -1.0f;
        float c1 = (n & 2) ? 1.0f : -1.0f;
        float c2 = (n & 1) ? 1.0f : -1.0f;
        float c[3] = {c0, c1, c2};
#pragma unroll
        for (int i = 0; i < 3; ++i) {
            float s  = 0.8f + 0.2f * u[(b * 8 + n) * 3 + i]; // (1-SCALE)+SCALE*u
            float bi = c[i] * s;                              // Bmat[b][n][i]
            t[i][0] += c[0] * bi;
            t[i][1] += c[1] * bi;
            t[i][2] += c[2] * bi;
            t[i][3] += bi;                                    // A[n][3] = 1
        }
    }
#pragma unroll
    for (int i = 0; i < 3; ++i)
#pragma unroll
        for (int j = 0; j < 4; ++j)
            T[b * 12 + i * 4 + j] = t[i][j] * 0.125f;
}

// ---------------------------------------------------------------------------
// Kernel 2: affine grid + trilinear resample with zero boundary.
// One thread per output voxel. Per-dim weights are zeroed when the source
// index is out of range -> product equals reference's `valid` masking.
// ---------------------------------------------------------------------------
__global__ __launch_bounds__(256) void warp_resample_kernel(
        const float* __restrict__ img, const float* __restrict__ T,
        float* __restrict__ out) {
    int idx = blockIdx.x * 256 + threadIdx.x;
    int b   = idx >> 21;              // 2^21 voxels per batch; uniform per block
    int rem = idx & (VOXELS_PER_B - 1);
    int d   = rem >> 14;
    int h   = (rem >> 7) & (NS - 1);
    int w   = rem & (NS - 1);

    __shared__ float t[12];
    if (threadIdx.x < 12) t[threadIdx.x] = T[b * 12 + threadIdx.x];
    __syncthreads();

    const float inv = 2.0f / 127.0f;  // linspace(-1,1,128) step
    float x = -1.0f + d * inv;
    float y = -1.0f + h * inv;
    float z = -1.0f + w * inv;

    // pixel coords: (affine(x,y,z,1) + 1) * (size-1)/2
    float p0 = (t[0] * x + t[1] * y + t[2]  * z + t[3]  + 1.0f) * 63.5f;
    float p1 = (t[4] * x + t[5] * y + t[6]  * z + t[7]  + 1.0f) * 63.5f;
    float p2 = (t[8] * x + t[9] * y + t[10] * z + t[11] + 1.0f) * 63.5f;

    float f0 = floorf(p0), f1 = floorf(p1), f2 = floorf(p2);
    int   i0 = (int)f0,    i1 = (int)f1,    i2 = (int)f2;
    float r0 = p0 - f0,    r1 = p1 - f1,    r2 = p2 - f2;

    // per-dim weights, zeroed when out of range (zero-boundary semantics)
    float wd0 = (i0 >= 0     && i0 < NS)     ? (1.0f - r0) : 0.0f;
    float wd1 = (i0 + 1 >= 0 && i0 + 1 < NS) ? r0          : 0.0f;
    float wh0 = (i1 >= 0     && i1 < NS)     ? (1.0f - r1) : 0.0f;
    float wh1 = (i1 + 1 >= 0 && i1 + 1 < NS) ? r1          : 0.0f;
    float ww0 = (i2 >= 0     && i2 < NS)     ? (1.0f - r2) : 0.0f;
    float ww1 = (i2 + 1 >= 0 && i2 + 1 < NS) ? r2          : 0.0f;

    // clipped indices for the gathers (matches reference's jnp.clip)
    int cd0 = min(max(i0,     0), NS - 1);
    int cd1 = min(max(i0 + 1, 0), NS - 1);
    int ch0 = min(max(i1,     0), NS - 1);
    int ch1 = min(max(i1 + 1, 0), NS - 1);
    int cw0 = min(max(i2,     0), NS - 1);
    int cw1 = min(max(i2 + 1, 0), NS - 1);

    const float* base = img + (size_t)b * VOXELS_PER_B;
    int r00 = (cd0 * NS + ch0) * NS;
    int r01 = (cd0 * NS + ch1) * NS;
    int r10 = (cd1 * NS + ch0) * NS;
    int r11 = (cd1 * NS + ch1) * NS;

    float v000 = base[r00 + cw0], v001 = base[r00 + cw1];
    float v010 = base[r01 + cw0], v011 = base[r01 + cw1];
    float v100 = base[r10 + cw0], v101 = base[r10 + cw1];
    float v110 = base[r11 + cw0], v111 = base[r11 + cw1];

    float acc = v000 * (wd0 * wh0 * ww0)
              + v001 * (wd0 * wh0 * ww1)
              + v010 * (wd0 * wh1 * ww0)
              + v011 * (wd0 * wh1 * ww1)
              + v100 * (wd1 * wh0 * ww0)
              + v101 * (wd1 * wh0 * ww1)
              + v110 * (wd1 * wh1 * ww0)
              + v111 * (wd1 * wh1 * ww1);

    out[idx] = acc;
}

extern "C" void kernel_launch(void* const* d_in, const int* in_sizes, int n_in,
                              void* d_out, int out_size, void* d_ws, size_t ws_size,
                              hipStream_t stream) {
    const float* img = (const float*)d_in[0];   // [8,128,128,128,1] fp32
    const float* u   = (const float*)d_in[1];   // [8,8,3] fp32
    float* out = (float*)d_out;
    float* T   = (float*)d_ws;                  // 8*12 floats of scratch

    affine_from_noise_kernel<<<1, 64, 0, stream>>>(u, T);

    int total  = NB * VOXELS_PER_B;             // 16,777,216
    int blocks = total / 256;                   // 65,536
    warp_resample_kernel<<<blocks, 256, 0, stream>>>(img, T, out);
}

// Round 2
// 146.072 us; speedup vs baseline: 1.1323x; 1.1323x over previous
//
#include <hip/hip_runtime.h>

// Problem constants (fixed by the reference setup_inputs):
//   input_tensor: [8, 128, 128, 128, 1] fp32
//   random_u:     [8, 8, 3] fp32
//   SCALE = 0.2
#define NB   8
#define NS   128          // D = H = W = 128
#define VOXELS_PER_B (NS*NS*NS)   // 2^21

// ---------------------------------------------------------------------------
// Kernel 1: per-batch affine transform from noise.
// A^T A = 8*I exactly (corner matrix rows are +-1) -> X = (A^T B)/8.
// Emit rows i=0..2 of transform = X^T (12 floats per batch).
// ---------------------------------------------------------------------------
__global__ void affine_from_noise_kernel(const float* __restrict__ u,
                                         float* __restrict__ T) {
    int b = threadIdx.x;
    if (b >= NB) return;
    float t[3][4];
#pragma unroll
    for (int i = 0; i < 3; ++i)
#pragma unroll
        for (int j = 0; j < 4; ++j) t[i][j] = 0.0f;

#pragma unroll
    for (int n = 0; n < 8; ++n) {
        float c0 = (n & 4) ? 1.0f : -1.0f;
        float c1 = (n & 2) ? 1.0f : -1.0f;
        float c2 = (n & 1) ? 1.0f : -1.0f;
        float c[3] = {c0, c1, c2};
#pragma unroll
        for (int i = 0; i < 3; ++i) {
            float s  = 0.8f + 0.2f * u[(b * 8 + n) * 3 + i];
            float bi = c[i] * s;
            t[i][0] += c[0] * bi;
            t[i][1] += c[1] * bi;
            t[i][2] += c[2] * bi;
            t[i][3] += bi;
        }
    }
#pragma unroll
    for (int i = 0; i < 3; ++i)
#pragma unroll
        for (int j = 0; j < 4; ++j)
            T[b * 12 + i * 4 + j] = t[i][j] * 0.125f;
}

// ---------------------------------------------------------------------------
// Kernel 2: affine grid + trilinear resample, 4 output voxels per thread
// along w. Wave-uniform fast path (all taps interior) skips clamping and
// uses one base pointer + immediate offsets for the 8 gathers.
// ---------------------------------------------------------------------------
__global__ __launch_bounds__(256) void warp_resample_kernel(
        const float* __restrict__ img, const float* __restrict__ T,
        float* __restrict__ out) {
    int gid   = blockIdx.x * 256 + threadIdx.x;
    int obase = gid << 2;                       // 4 consecutive w's (never crosses a row)
    int rem   = obase & (VOXELS_PER_B - 1);
    int d     = rem >> 14;
    int h     = (rem >> 7) & (NS - 1);
    int w     = rem & (NS - 1);

    __shared__ float t[12];
    int b = (int)((blockIdx.x * 1024u) >> 21);  // uniform per block (1024 | 2^21)
    if (threadIdx.x < 12) t[threadIdx.x] = T[b * 12 + threadIdx.x];
    __syncthreads();

    const float inv = 2.0f / 127.0f;            // linspace(-1,1,128) step
    float x = -1.0f + d * inv;
    float y = -1.0f + h * inv;
    float z = -1.0f + w * inv;

    // pixel coords: (affine(x,y,z,1) + 1) * 63.5 ; per-w step is exactly t[i*4+2]
    float q0 = (t[0] * x + t[1] * y + t[2]  * z + t[3]  + 1.0f) * 63.5f;
    float q1 = (t[4] * x + t[5] * y + t[6]  * z + t[7]  + 1.0f) * 63.5f;
    float q2 = (t[8] * x + t[9] * y + t[10] * z + t[11] + 1.0f) * 63.5f;
    float dp0 = t[2], dp1 = t[6], dp2 = t[10];

    const float* __restrict__ base = img + (size_t)b * VOXELS_PER_B;
    float res[4];

#pragma unroll
    for (int k = 0; k < 4; ++k) {
        float f0 = floorf(q0), f1 = floorf(q1), f2 = floorf(q2);
        int   i0 = (int)f0,    i1 = (int)f1,    i2 = (int)f2;
        float r0 = q0 - f0,    r1 = q1 - f1,    r2 = q2 - f2;

        bool ok = ((unsigned)i0 < 127u) && ((unsigned)i1 < 127u) &&
                  ((unsigned)i2 < 127u);
        float acc;
        if (__all(ok)) {
            // interior: no clamping, one base + immediate offsets
            const float* p = base + (((i0 << 7) + i1) << 7) + i2;
            float v000 = p[0],            v001 = p[1];
            float v010 = p[NS],           v011 = p[NS + 1];
            float v100 = p[NS * NS],      v101 = p[NS * NS + 1];
            float v110 = p[NS * NS + NS], v111 = p[NS * NS + NS + 1];
            float a0 = v000 + r2 * (v001 - v000);
            float a1 = v010 + r2 * (v011 - v010);
            float a2 = v100 + r2 * (v101 - v100);
            float a3 = v110 + r2 * (v111 - v110);
            float b0 = a0 + r1 * (a1 - a0);
            float b1 = a2 + r1 * (a3 - a2);
            acc = b0 + r0 * (b1 - b0);
        } else {
            // boundary: reference semantics (clip indices, zero weights)
            float wd0 = (i0 >= 0     && i0 < NS)     ? (1.0f - r0) : 0.0f;
            float wd1 = (i0 + 1 >= 0 && i0 + 1 < NS) ? r0          : 0.0f;
            float wh0 = (i1 >= 0     && i1 < NS)     ? (1.0f - r1) : 0.0f;
            float wh1 = (i1 + 1 >= 0 && i1 + 1 < NS) ? r1          : 0.0f;
            float ww0 = (i2 >= 0     && i2 < NS)     ? (1.0f - r2) : 0.0f;
            float ww1 = (i2 + 1 >= 0 && i2 + 1 < NS) ? r2          : 0.0f;

            int cd0 = min(max(i0,     0), NS - 1);
            int cd1 = min(max(i0 + 1, 0), NS - 1);
            int ch0 = min(max(i1,     0), NS - 1);
            int ch1 = min(max(i1 + 1, 0), NS - 1);
            int cw0 = min(max(i2,     0), NS - 1);
            int cw1 = min(max(i2 + 1, 0), NS - 1);

            int r00 = (cd0 * NS + ch0) * NS;
            int r01 = (cd0 * NS + ch1) * NS;
            int r10 = (cd1 * NS + ch0) * NS;
            int r11 = (cd1 * NS + ch1) * NS;

            float v000 = base[r00 + cw0], v001 = base[r00 + cw1];
            float v010 = base[r01 + cw0], v011 = base[r01 + cw1];
            float v100 = base[r10 + cw0], v101 = base[r10 + cw1];
            float v110 = base[r11 + cw0], v111 = base[r11 + cw1];

            acc = v000 * (wd0 * wh0 * ww0)
                + v001 * (wd0 * wh0 * ww1)
                + v010 * (wd0 * wh1 * ww0)
                + v011 * (wd0 * wh1 * ww1)
                + v100 * (wd1 * wh0 * ww0)
                + v101 * (wd1 * wh0 * ww1)
                + v110 * (wd1 * wh1 * ww0)
                + v111 * (wd1 * wh1 * ww1);
        }
        res[k] = acc;
        q0 += dp0; q1 += dp1; q2 += dp2;
    }

    float4 o = make_float4(res[0], res[1], res[2], res[3]);
    *reinterpret_cast<float4*>(out + obase) = o;
}

extern "C" void kernel_launch(void* const* d_in, const int* in_sizes, int n_in,
                              void* d_out, int out_size, void* d_ws, size_t ws_size,
                              hipStream_t stream) {
    const float* img = (const float*)d_in[0];   // [8,128,128,128,1] fp32
    const float* u   = (const float*)d_in[1];   // [8,8,3] fp32
    float* out = (float*)d_out;
    float* T   = (float*)d_ws;                  // 8*12 floats of scratch

    affine_from_noise_kernel<<<1, 64, 0, stream>>>(u, T);

    int total   = NB * VOXELS_PER_B;            // 16,777,216
    int threads = total / 4;                    // 4 outputs per thread
    int blocks  = threads / 256;                // 16,384
    warp_resample_kernel<<<blocks, 256, 0, stream>>>(img, T, out);
}